// Round 14
// baseline (228.932 us; speedup 1.0000x reference)
//
#include <hip/hip_runtime.h>
#include <math.h>

#define EPSF 1e-8f

typedef _Float16 f16x8 __attribute__((ext_vector_type(8)));
typedef float f32x4 __attribute__((ext_vector_type(4)));

#define GLOAD_LDS16(g, l)                                                      \
  __builtin_amdgcn_global_load_lds(                                            \
      (const __attribute__((address_space(1))) unsigned int*)(g),              \
      (__attribute__((address_space(3))) unsigned int*)(l), 16, 0, 0)

#define WAITV(n) asm volatile("s_waitcnt vmcnt(" #n ")" ::: "memory")
#define BAR() __builtin_amdgcn_s_barrier()

__device__ __forceinline__ unsigned int ord_from_float(float f) {
  unsigned int u = __float_as_uint(f);
  return (u & 0x80000000u) ? ~u : (u | 0x80000000u);
}

__device__ __forceinline__ float float_from_ord(unsigned int o) {
  return (o & 0x80000000u) ? __uint_as_float(o & 0x7fffffffu)
                           : __uint_as_float(~o);
}

__device__ __forceinline__ unsigned long long shfl_xor_u64(unsigned long long x, int m) {
  int lo = __shfl_xor((int)(unsigned int)(x & 0xffffffffull), m, 64);
  int hi = __shfl_xor((int)(unsigned int)(x >> 32), m, 64);
  return ((unsigned long long)(unsigned int)hi << 32) | (unsigned int)lo;
}

// ---------------- merged prep kernel ----------------
// A: Acat rows [hi(log)|hi(log)|lo(log)|pad0] (stride KPA), s_in, packed-init.
// B: Bfrag fragment-contiguous layout: for virtual k' in [0,KPA), col j:
//    block (f = j/16)*NSTEP + ks (= k'/32); lane slot (q = (k'%32)/8)*16 + j%16;
//    16 B per lane slot = 8 halves of k'. Segments: [hi(tgt)|lo(tgt)|hi(tgt)|0].
//    This is byte-identical data to what the old LDS path delivered per lane.
__global__ __launch_bounds__(64) void prep_kernel(
    const float* __restrict__ inp, const float* __restrict__ tgt,
    _Float16* __restrict__ Acat, _Float16* __restrict__ Bfrag,
    float* __restrict__ s_in, float* __restrict__ s_st,
    unsigned long long* __restrict__ packed,
    int N, int M, int Npad, int Mpad, int D, int DP, int KPA) {
  const int r = blockIdx.x;
  const int NSTEP = KPA >> 5;
  if (r < Npad) {
    _Float16* row = Acat + (size_t)r * KPA;
    float s = 0.f;
    for (int d = threadIdx.x; d < DP; d += 64) {
      float lg = 0.f;
      if (r < N && d < D) {
        float x = inp[(size_t)r * D + d];
        s += x;
        lg = logf(x + EPSF);
      }
      _Float16 h = (_Float16)lg;
      _Float16 l = (_Float16)(lg - (float)h);
      row[d] = h;
      row[DP + d] = h;
      row[2 * DP + d] = l;
    }
    for (int d = threadIdx.x; d < KPA - 3 * DP; d += 64)
      row[3 * DP + d] = (_Float16)0.f;
    #pragma unroll
    for (int m = 1; m < 64; m <<= 1) s += __shfl_xor(s, m, 64);
    if (threadIdx.x == 0 && r < N) {
      s_in[r] = s;
      packed[r] = ~0ull;
    }
  }
  if (r < Mpad) {
    float s = 0.f;
    const int f = r >> 4;
    const int rl = r & 15;
    const int CH = KPA >> 3;  // virtual-k chunks of 8
    _Float16* const fb = Bfrag + (size_t)f * NSTEP * 512 + (size_t)rl * 8;
    for (int c = threadIdx.x; c < CH; c += 64) {
      int vk = c << 3;
      f16x8 v;
      int d0; bool lo_seg = false, valid = true;
      if (vk < DP) { d0 = vk; }
      else if (vk < 2 * DP) { d0 = vk - DP; lo_seg = true; }
      else if (vk < 3 * DP) { d0 = vk - 2 * DP; }
      else { valid = false; d0 = 0; }
      #pragma unroll
      for (int e = 0; e < 8; ++e) {
        float x = 0.f;
        int d = d0 + e;
        if (valid && r < M && d < D) {
          x = tgt[(size_t)r * D + d];
          if (vk < DP && x > 1.0f)
            s += x * logf(x) - x + 0.5f * logf(6.283185307179586f * x);
        }
        _Float16 h = (_Float16)x;
        v[e] = lo_seg ? (_Float16)(x - (float)h) : h;
      }
      // ks = c>>2, q = c&3
      *(f16x8*)(fb + ((size_t)(c >> 2) * 512 + (size_t)(c & 3) * 128)) = v;
    }
    #pragma unroll
    for (int m = 1; m < 64; m <<= 1) s += __shfl_xor(s, m, 64);
    if (threadIdx.x == 0 && r < M) s_st[r] = s;
  }
}

// ---------------- MFMA pair-min kernel ----------------
// 256x256 tile, 8 waves (2Mx4N), BK=32. A via LDS (2 bufs, 32 KB static,
// verified swizzle); B read DIRECTLY from L2 as fragment-contiguous coalesced
// register loads (compiler inserts counted vmcnt for them). Per step:
// STAGE_A(t+1) | LOADB(t+1 -> other reg set) | COMPUTE(t) | WAITV(0) | BAR.
#define BT 256

__global__ __launch_bounds__(512, 2) void mfma_pair_min_kernel(
    const _Float16* __restrict__ Acat, const _Float16* __restrict__ Bfrag,
    const float* __restrict__ s_st, unsigned long long* __restrict__ packed,
    int N, int M, int KPA, int gx) {
  __shared__ __align__(16) _Float16 Ash[2][8192];  // 2 bufs x 256 rows x 32 h
  const int t = threadIdx.x;
  const int lane = t & 63;
  const int wid = t >> 6;   // 0..7
  const int wr = wid >> 2;  // 0..1 -> 128 output rows
  const int wc = wid & 3;   // 0..3 -> 64 output cols
  const int NSTEP = KPA >> 5;

  // XCD chunking + column-major traversal inside each chunk (round-6 verified)
  const int nwg = gridDim.x;
  const int q8 = nwg >> 3;
  const int xcd = blockIdx.x & 7;
  const int i8 = blockIdx.x >> 3;
  int brow, bcol;
  if (q8 % gx == 0) {
    int bh = q8 / gx;
    brow = xcd * bh + i8 % bh;
    bcol = i8 / bh;
  } else {
    int wg = xcd * q8 + i8;
    brow = wg / gx;
    bcol = wg % gx;
  }
  const int row0 = brow * BT;
  const int col0 = bcol * BT;

  f32x4 acc[8][4] = {};

  // A staging (verified swizzle): LDS dest linear; global source slot
  // pre-swizzled: LDS(r,s) = global(r, s^((r>>1)&3)). 0 bank conflicts.
  const int srow = lane >> 2;
  const int gs = (lane & 3) ^ ((lane >> 3) & 3);
  const _Float16* const a0 = Acat + (size_t)(row0 + wid * 32 + srow) * KPA + gs * 8;
  const _Float16* const a1 = a0 + (size_t)16 * KPA;

#define STAGEA(buf_, step_)                                                    \
  do {                                                                         \
    GLOAD_LDS16(a0 + (size_t)(step_) * 32, &Ash[buf_][wid * 1024]);            \
    GLOAD_LDS16(a1 + (size_t)(step_) * 32, &Ash[buf_][wid * 1024 + 512]);      \
  } while (0)

  // B fragment base for this wave: blocks f = bcol*16 + wc*4 + n
  const _Float16* const Bf =
      Bfrag + (size_t)(bcol * 16 + wc * 4) * NSTEP * 512 + (size_t)lane * 8;

#define LOADB(dst_, ks_)                                                       \
  do {                                                                         \
    _Pragma("unroll")                                                          \
    for (int n = 0; n < 4; ++n)                                                \
      dst_[n] = *(const f16x8*)(Bf + ((size_t)n * NSTEP + (ks_)) * 512);       \
  } while (0)

  const int rl = lane & 15;
  const int qq = lane >> 4;
  const int sa = qq ^ ((rl >> 1) & 3);  // swizzled k-slot

#define COMPUTE(buf_, BF_)                                                     \
  do {                                                                         \
    f16x8 af[8];                                                               \
    _Pragma("unroll")                                                          \
    for (int m = 0; m < 8; ++m)                                                \
      af[m] = *(const f16x8*)(&Ash[buf_][(wr * 128 + m * 16 + rl) * 32 + sa * 8]); \
    __builtin_amdgcn_s_setprio(1);                                             \
    _Pragma("unroll")                                                          \
    for (int m = 0; m < 8; ++m)                                                \
      _Pragma("unroll")                                                        \
      for (int n = 0; n < 4; ++n)                                              \
        acc[m][n] = __builtin_amdgcn_mfma_f32_16x16x32_f16(af[m], BF_[n],      \
                                                           acc[m][n], 0, 0, 0); \
    __builtin_amdgcn_s_setprio(0);                                             \
  } while (0)

#define BODY(T_, CUR_, NXT_)                                                   \
  do {                                                                         \
    STAGEA(((T_) + 1) & 1, (T_) + 1);                                          \
    LOADB(NXT_, (T_) + 1);                                                     \
    COMPUTE((T_) & 1, CUR_);                                                   \
    WAITV(0);                                                                  \
    BAR();                                                                     \
  } while (0)

  f16x8 bfA[4], bfB[4];
  const int NT = NSTEP;  // even (KPA multiple of 64)

  STAGEA(0, 0);
  LOADB(bfA, 0);
  WAITV(0);
  BAR();

  for (int kt = 0; kt < NT - 2; kt += 2) {
    BODY(kt, bfA, bfB);
    BODY(kt + 1, bfB, bfA);
  }
  BODY(NT - 2, bfA, bfB);      // stages+loads step NT-1
  COMPUTE((NT - 1) & 1, bfB);  // final step

#undef STAGEA
#undef LOADB
#undef COMPUTE
#undef BODY

  // ---- fused min/argmin epilogue (r9/r11-verified, atomicMin) ----
  // C/D frag: col = lane&15, row = (lane>>4)*4 + reg   [guide §3, m89-verified]
  float stv[4];
  #pragma unroll
  for (int n = 0; n < 4; ++n) {
    int gj = col0 + wc * 64 + n * 16 + rl;
    stv[n] = (gj < M) ? s_st[gj] : __builtin_inff();
  }
  #pragma unroll
  for (int m = 0; m < 8; ++m) {
    #pragma unroll
    for (int g = 0; g < 4; ++g) {
      int grow = row0 + wr * 128 + m * 16 + qq * 4 + g;
      unsigned long long bst = ~0ull;
      #pragma unroll
      for (int n = 0; n < 4; ++n) {
        int gj = col0 + wc * 64 + n * 16 + rl;
        float val = stv[n] - acc[m][n][g];
        unsigned long long p =
            ((unsigned long long)ord_from_float(val) << 32) | (unsigned int)gj;
        if (p < bst) bst = p;
      }
      #pragma unroll
      for (int mm = 1; mm < 16; mm <<= 1) {
        unsigned long long o = shfl_xor_u64(bst, mm);
        if (o < bst) bst = o;
      }
      if (rl == 0 && grow < N) atomicMin(&packed[grow], bst);
    }
  }
}

// ---------------- reduce + final ----------------
__global__ __launch_bounds__(256) void reduce_kernel(
    const unsigned long long* __restrict__ packed,
    const float* __restrict__ s_in, float* __restrict__ out,
    unsigned long long* __restrict__ sumbuf, int N) {
  int i = blockIdx.x * 256 + threadIdx.x;
  double local = 0.0;
  if (i < N) {
    unsigned long long p = packed[i];
    out[1 + i] = (float)(unsigned int)(p & 0xffffffffull);
    float val = float_from_ord((unsigned int)(p >> 32));
    local = (double)(s_in[i] + val);
  }
  __shared__ double sh[256];
  sh[threadIdx.x] = local;
  __syncthreads();
  for (int o = 128; o > 0; o >>= 1) {
    if (threadIdx.x < o) sh[threadIdx.x] += sh[threadIdx.x + o];
    __syncthreads();
  }
  if (threadIdx.x == 0) {
    long long q = __double2ll_rn(sh[0] * 1048576.0);  // fixed-point: deterministic
    atomicAdd(sumbuf, (unsigned long long)q);
  }
}

__global__ void final_kernel(const unsigned long long* __restrict__ sumbuf,
                             float* __restrict__ out, int N) {
  if (threadIdx.x == 0)
    out[0] = (float)(((double)(long long)sumbuf[0] / 1048576.0) / (double)N);
}

extern "C" void kernel_launch(void* const* d_in, const int* in_sizes, int n_in,
                              void* d_out, int out_size, void* d_ws, size_t ws_size,
                              hipStream_t stream) {
  const float* inp = (const float*)d_in[0];
  const float* tgt = (const float*)d_in[1];
  float* out = (float*)d_out;

  int N = out_size - 1;  // outputs: [loss scalar, match[N]]
  int D = in_sizes[0] / N;
  int M = in_sizes[1] / D;

  int Npad = ((N + BT - 1) / BT) * BT;
  int Mpad = ((M + BT - 1) / BT) * BT;
  int DP = ((D + 31) / 32) * 32;
  int KPA = ((3 * DP + 63) / 64) * 64;  // 576 for D=180 -> NT=18 (even)
  int gx = Mpad / BT, gy = Npad / BT;

  char* ws = (char*)d_ws;
  size_t off = 0;
  float* s_in = (float*)(ws + off); off += (size_t)N * 4;
  float* s_st = (float*)(ws + off); off += (size_t)M * 4;
  off = (off + 15) & ~(size_t)15;
  unsigned long long* sumbuf = (unsigned long long*)(ws + off); off += 16;
  unsigned long long* packed = (unsigned long long*)(ws + off); off += (size_t)N * 8;
  off = (off + 15) & ~(size_t)15;
  _Float16* Acat = (_Float16*)(ws + off); off += (size_t)Npad * KPA * 2;
  _Float16* Bfrag = (_Float16*)(ws + off); off += (size_t)Mpad * KPA * 2;

  hipMemsetAsync(sumbuf, 0, 8, stream);

  int pgrid = Npad > Mpad ? Npad : Mpad;
  prep_kernel<<<pgrid, 64, 0, stream>>>(inp, tgt, Acat, Bfrag, s_in, s_st,
                                        packed, N, M, Npad, Mpad, D, DP, KPA);

  mfma_pair_min_kernel<<<gx * gy, 512, 0, stream>>>(Acat, Bfrag, s_st, packed,
                                                    N, M, KPA, gx);

  reduce_kernel<<<(N + 255) / 256, 256, 0, stream>>>(packed, s_in, out,
                                                     sumbuf, N);
  final_kernel<<<1, 64, 0, stream>>>(sumbuf, out, N);
}